// Round 6
// baseline (431.364 us; speedup 1.0000x reference)
//
#include <hip/hip_runtime.h>
#include <hip/hip_bf16.h>

#define N_NODES 50000
#define N_EDGES 800000
#define D_FEAT 128
#define HIDDEN 96
#define N_CLASSES 10
#define N_GRAPHS 64
#define POOL_SLICES 16
#define SCAN_BLOCKS ((N_NODES + 255) / 256)   // 196

// ---------------- graph preprocessing ----------------

__global__ void k_init(int* __restrict__ deg_i, float* __restrict__ pooled) {
    int i = blockIdx.x * 256 + threadIdx.x;
    if (i < N_NODES) deg_i[i] = 0;
    if (i < N_GRAPHS * HIDDEN) pooled[i] = 0.f;
}

// histogram + per-edge rank (atomicAdd returns old value = rank within dst)
__global__ void k_deg(const int* __restrict__ dst, int* __restrict__ deg_i,
                      int* __restrict__ rank) {
    int e = blockIdx.x * 256 + threadIdx.x;
    if (e < N_EDGES) rank[e] = atomicAdd(&deg_i[dst[e]], 1);
}

// phase 1: per-block sums of deg_i
__global__ __launch_bounds__(256) void k_partial(const int* __restrict__ deg_i,
                                                 int* __restrict__ bsum) {
    __shared__ int wsum[4];
    int i = blockIdx.x * 256 + threadIdx.x;
    int v = (i < N_NODES) ? deg_i[i] : 0;
    for (int o = 32; o > 0; o >>= 1) v += __shfl_down(v, o, 64);
    int lane = threadIdx.x & 63, wid = threadIdx.x >> 6;
    if (lane == 0) wsum[wid] = v;
    __syncthreads();
    if (threadIdx.x == 0) bsum[blockIdx.x] = wsum[0] + wsum[1] + wsum[2] + wsum[3];
}

// phase 2: single small block scans the block sums -> exclusive prefixes
__global__ __launch_bounds__(256) void k_scanblk(const int* __restrict__ bsum,
                                                 int* __restrict__ bpre) {
    __shared__ int s[256];
    int t = threadIdx.x;
    s[t] = (t < SCAN_BLOCKS) ? bsum[t] : 0;
    __syncthreads();
    for (int off = 1; off < 256; off <<= 1) {
        int v = s[t];
        int a = (t >= off) ? s[t - off] : 0;
        __syncthreads();
        s[t] = v + a;
        __syncthreads();
    }
    if (t <= SCAN_BLOCKS) bpre[t] = (t == 0) ? 0 : s[t - 1];  // exclusive
}

// phase 3: local exclusive scan + block prefix -> offs; also dinv
__global__ __launch_bounds__(256) void k_offs(const int* __restrict__ deg_i,
                                              const int* __restrict__ bpre,
                                              int* __restrict__ offs,
                                              float* __restrict__ dinv) {
    __shared__ int s[256];
    int t = threadIdx.x;
    int i = blockIdx.x * 256 + t;
    int d = (i < N_NODES) ? deg_i[i] : 0;
    s[t] = d;
    __syncthreads();
    for (int off = 1; off < 256; off <<= 1) {
        int v = s[t];
        int a = (t >= off) ? s[t - off] : 0;
        __syncthreads();
        s[t] = v + a;
        __syncthreads();
    }
    int incl = s[t];
    int excl = incl - d;
    if (i < N_NODES) {
        int o = bpre[blockIdx.x] + excl;
        offs[i] = o;
        dinv[i] = rsqrtf((float)(d + 1));  // +1 self-loop
        if (i == N_NODES - 1) offs[N_NODES] = o + d;
    }
}

// atomic-free CSR fill: slot = offs[dst] + rank
__global__ void k_fill(const int* __restrict__ src, const int* __restrict__ dst,
                       const int* __restrict__ rank, const int* __restrict__ offs,
                       int* __restrict__ csr_src) {
    int e = blockIdx.x * 256 + threadIdx.x;
    if (e >= N_EDGES) return;
    csr_src[offs[dst[e]] + rank[e]] = src[e];
}

// ---------------- per-layer matmul: hws = (h @ W) * dinv  (W is K x 96) ----------------
// Register-tiled: block = 256 thr, tile = 64 nodes x 96 f; thread = 2 nodes x 12 f.
// 64-node tile -> 782 blocks (~3/CU) for latency hiding; h float4 prefetched.

#define FMA12(HQ, W0, W1, W2, R)                                        \
    acc[R][0].x += (HQ) * (W0).x; acc[R][0].y += (HQ) * (W0).y;         \
    acc[R][0].z += (HQ) * (W0).z; acc[R][0].w += (HQ) * (W0).w;         \
    acc[R][1].x += (HQ) * (W1).x; acc[R][1].y += (HQ) * (W1).y;         \
    acc[R][1].z += (HQ) * (W1).z; acc[R][1].w += (HQ) * (W1).w;         \
    acc[R][2].x += (HQ) * (W2).x; acc[R][2].y += (HQ) * (W2).y;         \
    acc[R][2].z += (HQ) * (W2).z; acc[R][2].w += (HQ) * (W2).w;

#define QSTEP(COMP)                                                     \
    {                                                                   \
        float4 w0 = Wl[kw + jc + 0];                                    \
        float4 w1 = Wl[kw + jc + 1];                                    \
        float4 w2 = Wl[kw + jc + 2];                                    \
        FMA12(hva.COMP, w0, w1, w2, 0)                                  \
        FMA12(hvb.COMP, w0, w1, w2, 1)                                  \
        kw += 24;                                                       \
    }

template <int K>
__global__ __launch_bounds__(256) void k_mm(const float* __restrict__ h,
                                            const float* __restrict__ W,
                                            const float* __restrict__ dinv,
                                            float* __restrict__ hws) {
    constexpr int K4 = K / 4;
    __shared__ float4 Wl[K * 24];  // K x 96 floats
    int t = threadIdx.x;
    const float4* W4 = (const float4*)W;
    for (int q = t; q < K * 24; q += 256) Wl[q] = W4[q];
    __syncthreads();

    int i = t & 31, j = t >> 5;
    int n0 = blockIdx.x * 64 + i * 2;
    int jc = j * 3;  // float4 offset of f0 = j*12
    const float4* h4 = (const float4*)h;
    int na = n0     < N_NODES ? n0     : N_NODES - 1;
    int nb = n0 + 1 < N_NODES ? n0 + 1 : N_NODES - 1;
    size_t ra = (size_t)na * K4;
    size_t rb = (size_t)nb * K4;

    float4 acc[2][3];
    #pragma unroll
    for (int r = 0; r < 2; ++r)
        #pragma unroll
        for (int c = 0; c < 3; ++c) acc[r][c] = make_float4(0.f, 0.f, 0.f, 0.f);

    float4 hva = h4[ra];
    float4 hvb = h4[rb];
    for (int kk = 0; kk < K4; ++kk) {
        int kn = (kk + 1 < K4) ? kk + 1 : kk;
        float4 nxa = h4[ra + kn];
        float4 nxb = h4[rb + kn];
        int kw = 4 * kk * 24;
        QSTEP(x)
        QSTEP(y)
        QSTEP(z)
        QSTEP(w)
        hva = nxa;
        hvb = nxb;
    }

    float4* hw4 = (float4*)hws;
    #pragma unroll
    for (int r = 0; r < 2; ++r) {
        int n = n0 + r;
        if (n < N_NODES) {
            float dv = dinv[n];
            size_t b = (size_t)n * 24 + jc;
            #pragma unroll
            for (int c = 0; c < 3; ++c) {
                float4 a = acc[r][c];
                a.x *= dv; a.y *= dv; a.z *= dv; a.w *= dv;
                hw4[b + c] = a;
            }
        }
    }
}

// ------------- aggregation: h_out[n] = relu(b + dinv[n]*(hws[n] + sum_in hws[s])) -------------
// Feature-sliced for XCD L2 locality: fc = blockIdx%8 picks a 64B column slice
// (6 slices cover the 384B row; fc 6,7 exit). Under round-robin block->XCD
// dispatch each XCD gathers only 50000*64B = 3.2MB, fitting its 4MB L2.
// 4 lanes per node cooperatively fetch the 64B line (one float4 each).

__global__ __launch_bounds__(256) void k_agg(const float* __restrict__ hws,
                                             const float* __restrict__ dinv,
                                             const int* __restrict__ offs,
                                             const int* __restrict__ csr_src,
                                             const float* __restrict__ bias,
                                             float* __restrict__ hout) {
    int fc = blockIdx.x & 7;
    if (fc >= 6) return;
    int t = threadIdx.x;
    int n = (blockIdx.x >> 3) * 64 + (t >> 2);
    if (n >= N_NODES) return;
    int col = fc * 4 + (t & 3);   // float4 column 0..23

    const float4* hw4 = (const float4*)hws;
    float4 acc = hw4[(size_t)n * 24 + col];   // self-loop (already dinv[n]-scaled)
    int beg = offs[n], end = offs[n + 1];
    int i = beg;
    for (; i + 2 <= end; i += 2) {
        int s0 = csr_src[i];
        int s1 = csr_src[i + 1];
        float4 v0 = hw4[(size_t)s0 * 24 + col];
        float4 v1 = hw4[(size_t)s1 * 24 + col];
        acc.x += v0.x + v1.x; acc.y += v0.y + v1.y;
        acc.z += v0.z + v1.z; acc.w += v0.w + v1.w;
    }
    if (i < end) {
        int s0 = csr_src[i];
        float4 v0 = hw4[(size_t)s0 * 24 + col];
        acc.x += v0.x; acc.y += v0.y; acc.z += v0.z; acc.w += v0.w;
    }
    float di = dinv[n];
    float4 b = ((const float4*)bias)[col];
    acc.x = fmaxf(acc.x * di + b.x, 0.f);
    acc.y = fmaxf(acc.y * di + b.y, 0.f);
    acc.z = fmaxf(acc.z * di + b.z, 0.f);
    acc.w = fmaxf(acc.w * di + b.w, 0.f);
    ((float4*)hout)[(size_t)n * 24 + col] = acc;
}

// ------------- parallel mean-pool: 64 graphs x 16 slices -------------

__global__ __launch_bounds__(192) void k_pool(const float* __restrict__ h,
                                              const int* __restrict__ batch,
                                              float* __restrict__ pooled) {
    int g = blockIdx.x / POOL_SLICES;
    int slice = blockIdx.x % POOL_SLICES;
    int t = threadIdx.x;
    int f = t % HIDDEN;
    int j = t / HIDDEN;  // 0 or 1
    int lo = 0, hi = N_NODES;
    while (lo < hi) { int m = (lo + hi) >> 1; if (batch[m] < g) lo = m + 1; else hi = m; }
    int start = lo;
    hi = N_NODES;
    while (lo < hi) { int m = (lo + hi) >> 1; if (batch[m] < g + 1) lo = m + 1; else hi = m; }
    int end = lo;
    int len = end - start;
    int per = (len + POOL_SLICES - 1) / POOL_SLICES;
    int s0 = start + slice * per;
    int s1 = min(s0 + per, end);
    float acc = 0.f;
    for (int n = s0 + j; n < s1; n += 2) acc += h[(size_t)n * HIDDEN + f];
    atomicAdd(&pooled[g * HIDDEN + f], acc);
}

// ------------- MLP head, one block per graph -------------

__global__ __launch_bounds__(128) void k_head_mlp(const float* __restrict__ pooled_in,
                                                  const int* __restrict__ batch,
                                                  const float* __restrict__ lw1,
                                                  const float* __restrict__ lb1,
                                                  const float* __restrict__ lw2,
                                                  const float* __restrict__ lb2,
                                                  float* __restrict__ out) {
    __shared__ float pooled[HIDDEN];
    __shared__ float zbuf[HIDDEN];
    int g = blockIdx.x;
    int t = threadIdx.x;
    int lo = 0, hi = N_NODES;
    while (lo < hi) { int m = (lo + hi) >> 1; if (batch[m] < g) lo = m + 1; else hi = m; }
    int start = lo;
    hi = N_NODES;
    while (lo < hi) { int m = (lo + hi) >> 1; if (batch[m] < g + 1) lo = m + 1; else hi = m; }
    int end = lo;
    float cnt = fmaxf((float)(end - start), 1.f);
    if (t < HIDDEN) pooled[t] = pooled_in[g * HIDDEN + t] / cnt;
    __syncthreads();
    if (t < HIDDEN) {
        float a = lb1[t];
        for (int k = 0; k < HIDDEN; ++k) a += pooled[k] * lw1[k * HIDDEN + t];
        zbuf[t] = fmaxf(a, 0.f);
    }
    __syncthreads();
    if (t < N_CLASSES) {
        float a = lb2[t];
        for (int k = 0; k < HIDDEN; ++k) a += zbuf[k] * lw2[k * N_CLASSES + t];
        out[g * N_CLASSES + t] = a;
    }
}

// ---------------- launch ----------------

extern "C" void kernel_launch(void* const* d_in, const int* in_sizes, int n_in,
                              void* d_out, int out_size, void* d_ws, size_t ws_size,
                              hipStream_t stream) {
    const float* x   = (const float*)d_in[0];
    const int*   ei  = (const int*)d_in[1];   // [2, E]
    const int*   bat = (const int*)d_in[2];
    const float* W1  = (const float*)d_in[3];
    const float* b1  = (const float*)d_in[4];
    const float* W2  = (const float*)d_in[5];
    const float* b2  = (const float*)d_in[6];
    const float* W3  = (const float*)d_in[7];
    const float* b3  = (const float*)d_in[8];
    const float* lw1 = (const float*)d_in[9];
    const float* lb1 = (const float*)d_in[10];
    const float* lw2 = (const float*)d_in[11];
    const float* lb2 = (const float*)d_in[12];
    float* out = (float*)d_out;

    const int* src = ei;
    const int* dst = ei + N_EDGES;

    // workspace carve-up (256B aligned)
    char* ws = (char*)d_ws;
    size_t off = 0;
    auto alloc = [&](size_t bytes) {
        size_t p = off;
        off = (off + bytes + 255) & ~(size_t)255;
        return p;
    };
    float* dinv    = (float*)(ws + alloc(sizeof(float) * N_NODES));
    int*   deg_i   = (int*)  (ws + alloc(sizeof(int) * N_NODES));
    int*   offs    = (int*)  (ws + alloc(sizeof(int) * (N_NODES + 1)));
    int*   bsum    = (int*)  (ws + alloc(sizeof(int) * (SCAN_BLOCKS + 1)));
    int*   bpre    = (int*)  (ws + alloc(sizeof(int) * (SCAN_BLOCKS + 1)));
    int*   rank    = (int*)  (ws + alloc(sizeof(int) * N_EDGES));
    int*   csr_src = (int*)  (ws + alloc(sizeof(int) * N_EDGES));
    float* bufA    = (float*)(ws + alloc(sizeof(float) * (size_t)N_NODES * HIDDEN));
    float* bufB    = (float*)(ws + alloc(sizeof(float) * (size_t)N_NODES * HIDDEN));
    float* pooled  = (float*)(ws + alloc(sizeof(float) * N_GRAPHS * HIDDEN));
    (void)ws_size;

    const int nodeBlocks = (N_NODES + 255) / 256;
    const int edgeBlocks = (N_EDGES + 255) / 256;
    const int mmBlocks   = (N_NODES + 63) / 64;            // 782
    const int aggBlocks  = ((N_NODES + 63) / 64) * 8;      // 6256 (fc-sliced)

    k_init<<<nodeBlocks, 256, 0, stream>>>(deg_i, pooled);
    k_deg<<<edgeBlocks, 256, 0, stream>>>(dst, deg_i, rank);
    k_partial<<<SCAN_BLOCKS, 256, 0, stream>>>(deg_i, bsum);
    k_scanblk<<<1, 256, 0, stream>>>(bsum, bpre);
    k_offs<<<SCAN_BLOCKS, 256, 0, stream>>>(deg_i, bpre, offs, dinv);
    k_fill<<<edgeBlocks, 256, 0, stream>>>(src, dst, rank, offs, csr_src);

    // layer 1: x (K=128)
    k_mm<D_FEAT><<<mmBlocks, 256, 0, stream>>>(x, W1, dinv, bufA);
    k_agg<<<aggBlocks, 256, 0, stream>>>(bufA, dinv, offs, csr_src, b1, bufB);
    // layer 2
    k_mm<HIDDEN><<<mmBlocks, 256, 0, stream>>>(bufB, W2, dinv, bufA);
    k_agg<<<aggBlocks, 256, 0, stream>>>(bufA, dinv, offs, csr_src, b2, bufB);
    // layer 3
    k_mm<HIDDEN><<<mmBlocks, 256, 0, stream>>>(bufB, W3, dinv, bufA);
    k_agg<<<aggBlocks, 256, 0, stream>>>(bufA, dinv, offs, csr_src, b3, bufB);

    k_pool<<<N_GRAPHS * POOL_SLICES, 192, 0, stream>>>(bufB, bat, pooled);
    k_head_mlp<<<N_GRAPHS, 128, 0, stream>>>(pooled, bat, lw1, lb1, lw2, lb2, out);
}

// Round 7
// 265.841 us; speedup vs baseline: 1.6226x; 1.6226x over previous
//
#include <hip/hip_runtime.h>
#include <hip/hip_fp16.h>

#define N_NODES 50000
#define N_EDGES 800000
#define D_FEAT 128
#define HIDDEN 96
#define N_CLASSES 10
#define N_GRAPHS 64
#define POOL_SLICES 16
#define SCAN_BLOCKS ((N_NODES + 255) / 256)   // 196

union F4H8 { float4 f; __half2 h[4]; };

__device__ inline uint2 pack4(float a, float b, float c, float d) {
    union { uint2 u; __half2 h[2]; } p;
    p.h[0] = __floats2half2_rn(a, b);
    p.h[1] = __floats2half2_rn(c, d);
    return p.u;
}

// ---------------- graph preprocessing ----------------

__global__ void k_init(int* __restrict__ deg_i, float* __restrict__ pooled) {
    int i = blockIdx.x * 256 + threadIdx.x;
    if (i < N_NODES) deg_i[i] = 0;
    if (i < N_GRAPHS * HIDDEN) pooled[i] = 0.f;
}

// histogram + per-edge rank (atomicAdd returns old value = rank within dst)
__global__ void k_deg(const int* __restrict__ dst, int* __restrict__ deg_i,
                      int* __restrict__ rank) {
    int e = blockIdx.x * 256 + threadIdx.x;
    if (e < N_EDGES) rank[e] = atomicAdd(&deg_i[dst[e]], 1);
}

__global__ __launch_bounds__(256) void k_partial(const int* __restrict__ deg_i,
                                                 int* __restrict__ bsum) {
    __shared__ int wsum[4];
    int i = blockIdx.x * 256 + threadIdx.x;
    int v = (i < N_NODES) ? deg_i[i] : 0;
    for (int o = 32; o > 0; o >>= 1) v += __shfl_down(v, o, 64);
    int lane = threadIdx.x & 63, wid = threadIdx.x >> 6;
    if (lane == 0) wsum[wid] = v;
    __syncthreads();
    if (threadIdx.x == 0) bsum[blockIdx.x] = wsum[0] + wsum[1] + wsum[2] + wsum[3];
}

__global__ __launch_bounds__(256) void k_scanblk(const int* __restrict__ bsum,
                                                 int* __restrict__ bpre) {
    __shared__ int s[256];
    int t = threadIdx.x;
    s[t] = (t < SCAN_BLOCKS) ? bsum[t] : 0;
    __syncthreads();
    for (int off = 1; off < 256; off <<= 1) {
        int v = s[t];
        int a = (t >= off) ? s[t - off] : 0;
        __syncthreads();
        s[t] = v + a;
        __syncthreads();
    }
    if (t <= SCAN_BLOCKS) bpre[t] = (t == 0) ? 0 : s[t - 1];  // exclusive
}

__global__ __launch_bounds__(256) void k_offs(const int* __restrict__ deg_i,
                                              const int* __restrict__ bpre,
                                              int* __restrict__ offs,
                                              float* __restrict__ dinv) {
    __shared__ int s[256];
    int t = threadIdx.x;
    int i = blockIdx.x * 256 + t;
    int d = (i < N_NODES) ? deg_i[i] : 0;
    s[t] = d;
    __syncthreads();
    for (int off = 1; off < 256; off <<= 1) {
        int v = s[t];
        int a = (t >= off) ? s[t - off] : 0;
        __syncthreads();
        s[t] = v + a;
        __syncthreads();
    }
    int incl = s[t];
    int excl = incl - d;
    if (i < N_NODES) {
        int o = bpre[blockIdx.x] + excl;
        offs[i] = o;
        dinv[i] = rsqrtf((float)(d + 1));  // +1 self-loop
        if (i == N_NODES - 1) offs[N_NODES] = o + d;
    }
}

// atomic-free CSR fill: slot = offs[dst] + rank
__global__ void k_fill(const int* __restrict__ src, const int* __restrict__ dst,
                       const int* __restrict__ rank, const int* __restrict__ offs,
                       int* __restrict__ csr_src) {
    int e = blockIdx.x * 256 + threadIdx.x;
    if (e >= N_EDGES) return;
    csr_src[offs[dst[e]] + rank[e]] = src[e];
}

// ---------------- matmul: hws = (h @ W) * dinv, fp16 output ----------------
// block = 256 thr, tile = 64 nodes; thread = 2 nodes x 12 feats, f32 accumulate.

#define FMA12(HQ, W0, W1, W2, R)                                        \
    acc[R][0].x += (HQ) * (W0).x; acc[R][0].y += (HQ) * (W0).y;         \
    acc[R][0].z += (HQ) * (W0).z; acc[R][0].w += (HQ) * (W0).w;         \
    acc[R][1].x += (HQ) * (W1).x; acc[R][1].y += (HQ) * (W1).y;         \
    acc[R][1].z += (HQ) * (W1).z; acc[R][1].w += (HQ) * (W1).w;         \
    acc[R][2].x += (HQ) * (W2).x; acc[R][2].y += (HQ) * (W2).y;         \
    acc[R][2].z += (HQ) * (W2).z; acc[R][2].w += (HQ) * (W2).w;

__device__ inline void store_row_fp16(__half* dst, const float4 a0, const float4 a1,
                                      const float4 a2, float dv) {
    uint2* d2 = (uint2*)dst;   // 24-byte offsets -> 8B aligned
    d2[0] = pack4(a0.x * dv, a0.y * dv, a0.z * dv, a0.w * dv);
    d2[1] = pack4(a1.x * dv, a1.y * dv, a1.z * dv, a1.w * dv);
    d2[2] = pack4(a2.x * dv, a2.y * dv, a2.z * dv, a2.w * dv);
}

// layer-1: f32 input x (K = 128)
__global__ __launch_bounds__(256) void k_mm_f32(const float* __restrict__ h,
                                                const float* __restrict__ W,
                                                const float* __restrict__ dinv,
                                                __half* __restrict__ hws) {
    constexpr int K = D_FEAT, K4 = K / 4;
    __shared__ float4 Wl[K * 24];
    int t = threadIdx.x;
    const float4* W4 = (const float4*)W;
    for (int q = t; q < K * 24; q += 256) Wl[q] = W4[q];
    __syncthreads();

    int i = t & 31, j = t >> 5;
    int n0 = blockIdx.x * 64 + i * 2;
    int jc = j * 3;
    const float4* h4 = (const float4*)h;
    int na = n0     < N_NODES ? n0     : N_NODES - 1;
    int nb = n0 + 1 < N_NODES ? n0 + 1 : N_NODES - 1;
    size_t ra = (size_t)na * K4;
    size_t rb = (size_t)nb * K4;

    float4 acc[2][3];
    #pragma unroll
    for (int r = 0; r < 2; ++r)
        #pragma unroll
        for (int c = 0; c < 3; ++c) acc[r][c] = make_float4(0.f, 0.f, 0.f, 0.f);

    float4 hva = h4[ra];
    float4 hvb = h4[rb];
    for (int kk = 0; kk < K4; ++kk) {
        int kn = (kk + 1 < K4) ? kk + 1 : kk;
        float4 nxa = h4[ra + kn];
        float4 nxb = h4[rb + kn];
        int kw = 4 * kk * 24;
        {
            float4 w0 = Wl[kw + jc], w1 = Wl[kw + jc + 1], w2 = Wl[kw + jc + 2];
            FMA12(hva.x, w0, w1, w2, 0) FMA12(hvb.x, w0, w1, w2, 1) kw += 24;
        }
        {
            float4 w0 = Wl[kw + jc], w1 = Wl[kw + jc + 1], w2 = Wl[kw + jc + 2];
            FMA12(hva.y, w0, w1, w2, 0) FMA12(hvb.y, w0, w1, w2, 1) kw += 24;
        }
        {
            float4 w0 = Wl[kw + jc], w1 = Wl[kw + jc + 1], w2 = Wl[kw + jc + 2];
            FMA12(hva.z, w0, w1, w2, 0) FMA12(hvb.z, w0, w1, w2, 1) kw += 24;
        }
        {
            float4 w0 = Wl[kw + jc], w1 = Wl[kw + jc + 1], w2 = Wl[kw + jc + 2];
            FMA12(hva.w, w0, w1, w2, 0) FMA12(hvb.w, w0, w1, w2, 1) kw += 24;
        }
        hva = nxa;
        hvb = nxb;
    }

    #pragma unroll
    for (int r = 0; r < 2; ++r) {
        int n = n0 + r;
        if (n < N_NODES)
            store_row_fp16(hws + (size_t)n * HIDDEN + j * 12,
                           acc[r][0], acc[r][1], acc[r][2], dinv[n]);
    }
}

// layers 2,3: fp16 input h (K = 96)
__global__ __launch_bounds__(256) void k_mm_f16(const __half* __restrict__ h,
                                                const float* __restrict__ W,
                                                const float* __restrict__ dinv,
                                                __half* __restrict__ hws) {
    constexpr int K = HIDDEN, K8 = K / 8;   // 12 chunks of 8 halfs
    __shared__ float4 Wl[K * 24];
    int t = threadIdx.x;
    const float4* W4 = (const float4*)W;
    for (int q = t; q < K * 24; q += 256) Wl[q] = W4[q];
    __syncthreads();

    int i = t & 31, j = t >> 5;
    int n0 = blockIdx.x * 64 + i * 2;
    int jc = j * 3;
    const float4* h4 = (const float4*)h;   // row = 12 float4 (96 halfs)
    int na = n0     < N_NODES ? n0     : N_NODES - 1;
    int nb = n0 + 1 < N_NODES ? n0 + 1 : N_NODES - 1;
    size_t ra = (size_t)na * K8;
    size_t rb = (size_t)nb * K8;

    float4 acc[2][3];
    #pragma unroll
    for (int r = 0; r < 2; ++r)
        #pragma unroll
        for (int c = 0; c < 3; ++c) acc[r][c] = make_float4(0.f, 0.f, 0.f, 0.f);

    F4H8 hva, hvb;
    hva.f = h4[ra];
    hvb.f = h4[rb];
    for (int kc = 0; kc < K8; ++kc) {
        int kn = (kc + 1 < K8) ? kc + 1 : kc;
        F4H8 nxa, nxb;
        nxa.f = h4[ra + kn];
        nxb.f = h4[rb + kn];
        float ha[8], hb[8];
        #pragma unroll
        for (int q = 0; q < 4; ++q) {
            float2 pa = __half22float2(hva.h[q]);
            float2 pb = __half22float2(hvb.h[q]);
            ha[2 * q] = pa.x; ha[2 * q + 1] = pa.y;
            hb[2 * q] = pb.x; hb[2 * q + 1] = pb.y;
        }
        int kw = kc * 8 * 24;
        #pragma unroll
        for (int q = 0; q < 8; ++q) {
            float4 w0 = Wl[kw + jc], w1 = Wl[kw + jc + 1], w2 = Wl[kw + jc + 2];
            FMA12(ha[q], w0, w1, w2, 0)
            FMA12(hb[q], w0, w1, w2, 1)
            kw += 24;
        }
        hva = nxa;
        hvb = nxb;
    }

    #pragma unroll
    for (int r = 0; r < 2; ++r) {
        int n = n0 + r;
        if (n < N_NODES)
            store_row_fp16(hws + (size_t)n * HIDDEN + j * 12,
                           acc[r][0], acc[r][1], acc[r][2], dinv[n]);
    }
}

// ------------- aggregation: h_out[n] = relu(b + dinv[n]*(hws[n] + sum_in hws[s])) -------------
// fp16 rows (192B = 12 float4); thread = (node, 16B chunk of 8 feats); f32 accumulate.

__global__ __launch_bounds__(256) void k_agg(const __half* __restrict__ hws,
                                             const float* __restrict__ dinv,
                                             const int* __restrict__ offs,
                                             const int* __restrict__ csr_src,
                                             const float* __restrict__ bias,
                                             __half* __restrict__ hout) {
    int id = blockIdx.x * 256 + threadIdx.x;
    if (id >= N_NODES * 12) return;
    int c = id % 12;
    int n = id / 12;
    const float4* hw4 = (const float4*)hws;
    F4H8 v;
    v.f = hw4[(size_t)n * 12 + c];   // self-loop (already dinv[n]-scaled)
    float2 p0 = __half22float2(v.h[0]), p1 = __half22float2(v.h[1]);
    float2 p2 = __half22float2(v.h[2]), p3 = __half22float2(v.h[3]);
    float4 A = make_float4(p0.x, p0.y, p1.x, p1.y);
    float4 B = make_float4(p2.x, p2.y, p3.x, p3.y);

    int beg = offs[n], end = offs[n + 1];
    int i = beg;
    for (; i + 2 <= end; i += 2) {
        F4H8 v0, v1;
        v0.f = hw4[(size_t)csr_src[i] * 12 + c];
        v1.f = hw4[(size_t)csr_src[i + 1] * 12 + c];
        float2 a0 = __half22float2(v0.h[0]), a1 = __half22float2(v0.h[1]);
        float2 a2 = __half22float2(v0.h[2]), a3 = __half22float2(v0.h[3]);
        float2 b0 = __half22float2(v1.h[0]), b1 = __half22float2(v1.h[1]);
        float2 b2 = __half22float2(v1.h[2]), b3 = __half22float2(v1.h[3]);
        A.x += a0.x + b0.x; A.y += a0.y + b0.y;
        A.z += a1.x + b1.x; A.w += a1.y + b1.y;
        B.x += a2.x + b2.x; B.y += a2.y + b2.y;
        B.z += a3.x + b3.x; B.w += a3.y + b3.y;
    }
    if (i < end) {
        F4H8 v0;
        v0.f = hw4[(size_t)csr_src[i] * 12 + c];
        float2 a0 = __half22float2(v0.h[0]), a1 = __half22float2(v0.h[1]);
        float2 a2 = __half22float2(v0.h[2]), a3 = __half22float2(v0.h[3]);
        A.x += a0.x; A.y += a0.y; A.z += a1.x; A.w += a1.y;
        B.x += a2.x; B.y += a2.y; B.z += a3.x; B.w += a3.y;
    }

    float di = dinv[n];
    float4 b0 = ((const float4*)bias)[c * 2];
    float4 b1 = ((const float4*)bias)[c * 2 + 1];
    A.x = fmaxf(A.x * di + b0.x, 0.f); A.y = fmaxf(A.y * di + b0.y, 0.f);
    A.z = fmaxf(A.z * di + b0.z, 0.f); A.w = fmaxf(A.w * di + b0.w, 0.f);
    B.x = fmaxf(B.x * di + b1.x, 0.f); B.y = fmaxf(B.y * di + b1.y, 0.f);
    B.z = fmaxf(B.z * di + b1.z, 0.f); B.w = fmaxf(B.w * di + b1.w, 0.f);

    F4H8 o;
    o.h[0] = __floats2half2_rn(A.x, A.y);
    o.h[1] = __floats2half2_rn(A.z, A.w);
    o.h[2] = __floats2half2_rn(B.x, B.y);
    o.h[3] = __floats2half2_rn(B.z, B.w);
    ((float4*)hout)[(size_t)n * 12 + c] = o.f;
}

// ------------- parallel mean-pool: 64 graphs x 16 slices (fp16 input) -------------

__global__ __launch_bounds__(192) void k_pool(const __half* __restrict__ h,
                                              const int* __restrict__ batch,
                                              float* __restrict__ pooled) {
    int g = blockIdx.x / POOL_SLICES;
    int slice = blockIdx.x % POOL_SLICES;
    int t = threadIdx.x;
    int f = t % HIDDEN;
    int j = t / HIDDEN;  // 0 or 1
    int lo = 0, hi = N_NODES;
    while (lo < hi) { int m = (lo + hi) >> 1; if (batch[m] < g) lo = m + 1; else hi = m; }
    int start = lo;
    hi = N_NODES;
    while (lo < hi) { int m = (lo + hi) >> 1; if (batch[m] < g + 1) lo = m + 1; else hi = m; }
    int end = lo;
    int len = end - start;
    int per = (len + POOL_SLICES - 1) / POOL_SLICES;
    int s0 = start + slice * per;
    int s1 = min(s0 + per, end);
    float acc = 0.f;
    for (int n = s0 + j; n < s1; n += 2) acc += __half2float(h[(size_t)n * HIDDEN + f]);
    atomicAdd(&pooled[g * HIDDEN + f], acc);
}

// ------------- MLP head, one block per graph -------------

__global__ __launch_bounds__(128) void k_head_mlp(const float* __restrict__ pooled_in,
                                                  const int* __restrict__ batch,
                                                  const float* __restrict__ lw1,
                                                  const float* __restrict__ lb1,
                                                  const float* __restrict__ lw2,
                                                  const float* __restrict__ lb2,
                                                  float* __restrict__ out) {
    __shared__ float pooled[HIDDEN];
    __shared__ float zbuf[HIDDEN];
    int g = blockIdx.x;
    int t = threadIdx.x;
    int lo = 0, hi = N_NODES;
    while (lo < hi) { int m = (lo + hi) >> 1; if (batch[m] < g) lo = m + 1; else hi = m; }
    int start = lo;
    hi = N_NODES;
    while (lo < hi) { int m = (lo + hi) >> 1; if (batch[m] < g + 1) lo = m + 1; else hi = m; }
    int end = lo;
    float cnt = fmaxf((float)(end - start), 1.f);
    if (t < HIDDEN) pooled[t] = pooled_in[g * HIDDEN + t] / cnt;
    __syncthreads();
    if (t < HIDDEN) {
        float a = lb1[t];
        for (int k = 0; k < HIDDEN; ++k) a += pooled[k] * lw1[k * HIDDEN + t];
        zbuf[t] = fmaxf(a, 0.f);
    }
    __syncthreads();
    if (t < N_CLASSES) {
        float a = lb2[t];
        for (int k = 0; k < HIDDEN; ++k) a += zbuf[k] * lw2[k * N_CLASSES + t];
        out[g * N_CLASSES + t] = a;
    }
}

// ---------------- launch ----------------

extern "C" void kernel_launch(void* const* d_in, const int* in_sizes, int n_in,
                              void* d_out, int out_size, void* d_ws, size_t ws_size,
                              hipStream_t stream) {
    const float* x   = (const float*)d_in[0];
    const int*   ei  = (const int*)d_in[1];   // [2, E]
    const int*   bat = (const int*)d_in[2];
    const float* W1  = (const float*)d_in[3];
    const float* b1  = (const float*)d_in[4];
    const float* W2  = (const float*)d_in[5];
    const float* b2  = (const float*)d_in[6];
    const float* W3  = (const float*)d_in[7];
    const float* b3  = (const float*)d_in[8];
    const float* lw1 = (const float*)d_in[9];
    const float* lb1 = (const float*)d_in[10];
    const float* lw2 = (const float*)d_in[11];
    const float* lb2 = (const float*)d_in[12];
    float* out = (float*)d_out;

    const int* src = ei;
    const int* dst = ei + N_EDGES;

    // workspace carve-up (256B aligned)
    char* ws = (char*)d_ws;
    size_t off = 0;
    auto alloc = [&](size_t bytes) {
        size_t p = off;
        off = (off + bytes + 255) & ~(size_t)255;
        return p;
    };
    float*  dinv    = (float*) (ws + alloc(sizeof(float) * N_NODES));
    int*    deg_i   = (int*)   (ws + alloc(sizeof(int) * N_NODES));
    int*    offs    = (int*)   (ws + alloc(sizeof(int) * (N_NODES + 1)));
    int*    bsum    = (int*)   (ws + alloc(sizeof(int) * (SCAN_BLOCKS + 1)));
    int*    bpre    = (int*)   (ws + alloc(sizeof(int) * (SCAN_BLOCKS + 1)));
    int*    rank    = (int*)   (ws + alloc(sizeof(int) * N_EDGES));
    int*    csr_src = (int*)   (ws + alloc(sizeof(int) * N_EDGES));
    __half* bufA    = (__half*)(ws + alloc(sizeof(__half) * (size_t)N_NODES * HIDDEN));
    __half* bufB    = (__half*)(ws + alloc(sizeof(__half) * (size_t)N_NODES * HIDDEN));
    float*  pooled  = (float*) (ws + alloc(sizeof(float) * N_GRAPHS * HIDDEN));
    (void)ws_size;

    const int nodeBlocks = (N_NODES + 255) / 256;
    const int edgeBlocks = (N_EDGES + 255) / 256;
    const int mmBlocks   = (N_NODES + 63) / 64;           // 782
    const int aggBlocks  = (N_NODES * 12 + 255) / 256;    // 2344

    k_init<<<nodeBlocks, 256, 0, stream>>>(deg_i, pooled);
    k_deg<<<edgeBlocks, 256, 0, stream>>>(dst, deg_i, rank);
    k_partial<<<SCAN_BLOCKS, 256, 0, stream>>>(deg_i, bsum);
    k_scanblk<<<1, 256, 0, stream>>>(bsum, bpre);
    k_offs<<<SCAN_BLOCKS, 256, 0, stream>>>(deg_i, bpre, offs, dinv);
    k_fill<<<edgeBlocks, 256, 0, stream>>>(src, dst, rank, offs, csr_src);

    // layer 1: x (K=128, f32 in)
    k_mm_f32<<<mmBlocks, 256, 0, stream>>>(x, W1, dinv, bufA);
    k_agg<<<aggBlocks, 256, 0, stream>>>(bufA, dinv, offs, csr_src, b1, bufB);
    // layer 2 (fp16 in)
    k_mm_f16<<<mmBlocks, 256, 0, stream>>>(bufB, W2, dinv, bufA);
    k_agg<<<aggBlocks, 256, 0, stream>>>(bufA, dinv, offs, csr_src, b2, bufB);
    // layer 3 (fp16 in)
    k_mm_f16<<<mmBlocks, 256, 0, stream>>>(bufB, W3, dinv, bufA);
    k_agg<<<aggBlocks, 256, 0, stream>>>(bufA, dinv, offs, csr_src, b3, bufB);

    k_pool<<<N_GRAPHS * POOL_SLICES, 192, 0, stream>>>(bufB, bat, pooled);
    k_head_mlp<<<N_GRAPHS, 128, 0, stream>>>(pooled, bat, lw1, lb1, lw2, lb2, out);
}